// Round 2
// baseline (974.962 us; speedup 1.0000x reference)
//
#include <hip/hip_runtime.h>

#define SEQ_LEN 96
#define PRED_LEN 16
#define HIDDEN 64
#define FEAT 7
#define BATCH 512
#define GATES 256                 // 4*HIDDEN
#define TL (SEQ_LEN + PRED_LEN)   // 112-entry sliding timeline
#define XSTR 8                    // padded timeline stride (2x float4 loads)

__device__ __forceinline__ float sigmoidf_(float x) {
    return 1.0f / (1.0f + __expf(-x));
}
__device__ __forceinline__ float tanhf_(float x) {
    return 1.0f - 2.0f / (__expf(2.0f * x) + 1.0f);
}

// One block (256 threads = 4 waves) per batch element. Thread g owns gate g:
// W_hh row (16 float4 = 64 VGPRs) + W_ih row in registers. Each wave keeps a
// PRIVATE h replica in LDS (intra-wave write->read is wave-synchronous, no
// barrier), and the cell update is computed redundantly by all 4 waves, so the
// only cross-wave communication is the gate array -> ONE barrier per step via
// parity double-buffering.
__global__ __launch_bounds__(256, 2) void lstm_ar_kernel(
    const float* __restrict__ x,     // [B, 96, 7]
    const float* __restrict__ W_ih,  // [256, 7]
    const float* __restrict__ W_hh,  // [256, 64]
    const float* __restrict__ b_ih,  // [256]
    const float* __restrict__ b_hh,  // [256]
    const float* __restrict__ fc_W,  // [7, 64]
    const float* __restrict__ fc_b,  // [7]
    float* __restrict__ out)         // [B, 16, 7]
{
    __shared__ float xs[TL * XSTR];       // padded sliding input timeline
    __shared__ float hsw[4 * HIDDEN];     // per-wave private h replicas
    __shared__ float gbuf[2][GATES];      // parity double-buffered gates
    __shared__ float fcw[FEAT * HIDDEN];
    __shared__ float fcb[FEAT];

    const int tid  = threadIdx.x;
    const int b    = blockIdx.x;
    const int wv   = tid >> 6;            // wave id = gate class (i,f,g,o)
    const int lane = tid & 63;

    // ---- per-thread weight registers ----
    float4 whh4[16];
    const float4* wrow = (const float4*)(W_hh + tid * HIDDEN);  // 256B-aligned rows
    #pragma unroll
    for (int j = 0; j < 16; ++j) whh4[j] = wrow[j];

    float wih[FEAT];
    #pragma unroll
    for (int i = 0; i < FEAT; ++i) wih[i] = W_ih[tid * FEAT + i];
    const float bias = b_ih[tid] + b_hh[tid];

    // ---- stage inputs / init state ----
    for (int i = tid; i < SEQ_LEN * FEAT; i += 256) {
        int t = i / FEAT, f = i - t * FEAT;
        xs[t * XSTR + f] = x[b * SEQ_LEN * FEAT + i];
    }
    for (int i = tid; i < FEAT * HIDDEN; i += 256) fcw[i] = fc_W[i];
    if (tid < FEAT) fcb[tid] = fc_b[tid];
    hsw[tid] = 0.0f;                      // all 4 replicas zeroed (4*64 == 256)
    float c = 0.0f;                       // cell state: lane j of every wave holds c_j
    __syncthreads();

    int p = 0;                            // gate-buffer parity
    for (int k = 0; k < PRED_LEN; ++k) {
        for (int t = 0; t < SEQ_LEN; ++t) {
            const float4* xt4 = (const float4*)(xs + (k + t) * XSTR);
            float4 xa = xt4[0];
            float4 xb = xt4[1];           // .w is padding, unused

            float a0 = bias, a1 = 0.0f, a2 = 0.0f, a3 = 0.0f;
            a0 = fmaf(wih[0], xa.x, a0);
            a1 = fmaf(wih[1], xa.y, a1);
            a2 = fmaf(wih[2], xa.z, a2);
            a3 = fmaf(wih[3], xa.w, a3);
            a0 = fmaf(wih[4], xb.x, a0);
            a1 = fmaf(wih[5], xb.y, a1);
            a2 = fmaf(wih[6], xb.z, a2);

            const float4* h4 = (const float4*)(hsw + (wv << 6));
            #pragma unroll
            for (int j = 0; j < 16; ++j) {
                float4 hv = h4[j];
                float4 wr = whh4[j];
                a0 = fmaf(wr.x, hv.x, a0);
                a1 = fmaf(wr.y, hv.y, a1);
                a2 = fmaf(wr.z, hv.z, a2);
                a3 = fmaf(wr.w, hv.w, a3);
            }
            float acc = (a0 + a1) + (a2 + a3);

            // PyTorch gate order i,f,g,o -> wave 2 is tanh (wave-uniform branch)
            float act = (wv == 2) ? tanhf_(acc) : sigmoidf_(acc);
            gbuf[p][tid] = act;
            __syncthreads();              // the ONLY barrier per step

            // replicated cell update: lane j of every wave computes h_j, c_j
            float ig = gbuf[p][lane];
            float fg = gbuf[p][HIDDEN     + lane];
            float gg = gbuf[p][2 * HIDDEN + lane];
            float og = gbuf[p][3 * HIDDEN + lane];
            c = fmaf(fg, c, ig * gg);
            hsw[(wv << 6) + lane] = og * tanhf_(c);   // private replica: no barrier
            p ^= 1;
        }

        // ---- prediction head (wave 0 has a full h replica) ----
        if (tid < FEAT) {
            float p0 = fcb[tid], p1 = 0.0f, p2 = 0.0f, p3 = 0.0f;
            #pragma unroll
            for (int j = 0; j < HIDDEN; j += 4) {
                p0 = fmaf(fcw[tid * HIDDEN + j + 0], hsw[j + 0], p0);
                p1 = fmaf(fcw[tid * HIDDEN + j + 1], hsw[j + 1], p1);
                p2 = fmaf(fcw[tid * HIDDEN + j + 2], hsw[j + 2], p2);
                p3 = fmaf(fcw[tid * HIDDEN + j + 3], hsw[j + 3], p3);
            }
            float pred = (p0 + p1) + (p2 + p3);
            out[(b * PRED_LEN + k) * FEAT + tid] = pred;
            xs[(SEQ_LEN + k) * XSTR + tid] = pred;    // append to timeline
        }
        __syncthreads();                  // pred visible before consumption
    }
}

extern "C" void kernel_launch(void* const* d_in, const int* in_sizes, int n_in,
                              void* d_out, int out_size, void* d_ws, size_t ws_size,
                              hipStream_t stream) {
    const float* x    = (const float*)d_in[0];
    const float* W_ih = (const float*)d_in[1];
    const float* W_hh = (const float*)d_in[2];
    const float* b_ih = (const float*)d_in[3];
    const float* b_hh = (const float*)d_in[4];
    const float* fc_W = (const float*)d_in[5];
    const float* fc_b = (const float*)d_in[6];
    float* out = (float*)d_out;

    lstm_ar_kernel<<<BATCH, 256, 0, stream>>>(x, W_ih, W_hh, b_ih, b_hh, fc_W, fc_b, out);
}